// Round 5
// baseline (4503.246 us; speedup 1.0000x reference)
//
#include <hip/hip_runtime.h>
#include <math.h>

#define N_NODES 50000
#define N_EDGES 1000000
#define LAYERS  3
#define G_GRAPHS 512
#define H 128
#define NG 50
#define PI_F 3.14159265358979323846f
#define LOG2_F 0.6931471805599453f

__device__ __forceinline__ float ssp(float v) {
    float t = __expf(-fabsf(v));
    return fmaxf(v, 0.0f) + __logf(1.0f + t) - LOG2_F;
}

// -------------------- h = relu(emb[z]) --------------------
__global__ __launch_bounds__(256) void init_h(const int* __restrict__ z,
                                              const float* __restrict__ emb,
                                              float* __restrict__ h) {
    int idx = blockIdx.x * 256 + threadIdx.x;
    if (idx >= N_NODES * (H / 4)) return;
    int n = idx >> 5;
    int c4 = idx & 31;
    int zv = z[n];
    float4 v = *(const float4*)(emb + (size_t)zv * H + c4 * 4);
    v.x = fmaxf(v.x, 0.f); v.y = fmaxf(v.y, 0.f);
    v.z = fmaxf(v.z, 0.f); v.w = fmaxf(v.w, 0.f);
    *(float4*)(h + (size_t)n * H + c4 * 4) = v;
}

// -------------------- CSR build: sort edges by dst --------------------
__global__ __launch_bounds__(256) void hist_kernel(const int* __restrict__ edst,
                                                   int* __restrict__ cnt) {
    int e = blockIdx.x * 256 + threadIdx.x;
    if (e < N_EDGES) atomicAdd(&cnt[edst[e]], 1);
}

__global__ __launch_bounds__(1024) void scan_kernel(const int* __restrict__ cnt,
                                                    int* __restrict__ cur) {
    __shared__ int buf[1024];
    __shared__ int carry;
    int tid = threadIdx.x;
    if (tid == 0) carry = 0;
    __syncthreads();
    for (int base = 0; base < N_NODES; base += 1024) {
        int i = base + tid;
        int v = (i < N_NODES) ? cnt[i] : 0;
        int incl = v;
        buf[tid] = incl;
        __syncthreads();
        for (int s = 1; s < 1024; s <<= 1) {
            int t = (tid >= s) ? buf[tid - s] : 0;
            __syncthreads();
            incl += t;
            buf[tid] = incl;
            __syncthreads();
        }
        int cbase = carry;
        if (i < N_NODES) cur[i] = cbase + incl - v;
        __syncthreads();
        if (tid == 1023) carry = cbase + incl;
        __syncthreads();
    }
}

__global__ __launch_bounds__(256) void scatter_kernel(const int* __restrict__ edst,
                                                      int* __restrict__ cur,
                                                      int* __restrict__ perm) {
    int e = blockIdx.x * 256 + threadIdx.x;
    if (e < N_EDGES) {
        int p = atomicAdd(&cur[edst[e]], 1);
        perm[p] = e;
    }
}

// -------------------- presort: edge metadata + attrs into perm order --------------------
__global__ __launch_bounds__(256) void presort_meta(const float* __restrict__ ew,
                                                    const int* __restrict__ esrc,
                                                    const int* __restrict__ edst,
                                                    const int* __restrict__ perm,
                                                    int* __restrict__ esrc_s,
                                                    int* __restrict__ edst_s,
                                                    float* __restrict__ cw_s) {
    int i = blockIdx.x * 256 + threadIdx.x;
    if (i < N_EDGES) {
        int ge = perm[i];
        esrc_s[i] = esrc[ge];
        edst_s[i] = edst[ge];
        cw_s[i] = 0.5f * (cosf(ew[ge] * (PI_F / 10.0f)) + 1.0f);
    }
}

__global__ __launch_bounds__(256) void presort_attr(const float* __restrict__ eattr,
                                                    const int* __restrict__ perm,
                                                    float* __restrict__ eattr_s) {
    long long idx = (long long)blockIdx.x * 256 + threadIdx.x;   // e*64 + k
    int e = (int)(idx >> 6);
    int k = (int)(idx & 63);
    if (e < N_EDGES && k < NG)
        eattr_s[(size_t)e * NG + k] = eattr[(size_t)perm[e] * NG + k];
}

// -------------------- generic node GEMM (unchanged) --------------------
#define F_BIAS 1
#define F_SSPA 2
#define F_ACCUM 4
#define F_POOL 8

template <int FLAGS>
__global__ __launch_bounds__(256, 4) void node_gemm(const float* __restrict__ A,
                                                    const float* __restrict__ B,
                                                    const float* __restrict__ bias,
                                                    float* __restrict__ Out,
                                                    const int* __restrict__ batch,
                                                    int nRows, int NC) {
    __shared__ float Atc[128 * 65];
    int tid = threadIdx.x;
    int rowBase = blockIdx.x * 64;
    int colOff = blockIdx.y * 128;
    int rlim = nRows - rowBase; if (rlim > 64) rlim = 64;

    for (int idx = tid; idx < 64 * 128; idx += 256) {
        int r = idx >> 7, k = idx & 127;
        float v = 0.f;
        if (r < rlim) {
            v = A[(size_t)(rowBase + r) * H + k];
            if (FLAGS & F_SSPA) v = ssp(v);
        }
        Atc[k * 65 + r] = v;
    }
    __syncthreads();

    int cg = tid & 15, rg = tid >> 4;
    int r0 = rg * 4;
    int gc0 = colOff + cg * 4, gc1 = colOff + 64 + cg * 4;

    float acc[4][8];
#pragma unroll
    for (int j = 0; j < 4; ++j) {
        float b0 = 0.f, b1v = 0.f;
        if (FLAGS & F_BIAS) { b0 = bias[gc0 + j]; b1v = bias[gc1 + j]; }
#pragma unroll
        for (int i = 0; i < 4; ++i) { acc[i][j] = b0; acc[i][4 + j] = b1v; }
    }

#pragma unroll 4
    for (int k = 0; k < H; ++k) {
        float4 a4 = *(float4*)(Atc + k * 65 + r0);
        float4 w0 = *(const float4*)(B + (size_t)k * NC + gc0);
        float4 w1 = *(const float4*)(B + (size_t)k * NC + gc1);
        float av[4] = {a4.x, a4.y, a4.z, a4.w};
        float wv[8] = {w0.x, w0.y, w0.z, w0.w, w1.x, w1.y, w1.z, w1.w};
#pragma unroll
        for (int i = 0; i < 4; ++i)
#pragma unroll
            for (int j = 0; j < 8; ++j) acc[i][j] = fmaf(av[i], wv[j], acc[i][j]);
    }

    if (FLAGS & F_POOL) {
        int cur = -1;
        float sA[4] = {0, 0, 0, 0}, sB[4] = {0, 0, 0, 0};
#pragma unroll
        for (int i = 0; i < 4; ++i) {
            int r = r0 + i;
            int b = (r < rlim) ? batch[rowBase + r] : -1;
            if (b != cur) {
                if (cur >= 0) {
#pragma unroll
                    for (int j = 0; j < 4; ++j) {
                        unsafeAtomicAdd(Out + (size_t)cur * NC + gc0 + j, sA[j]);
                        unsafeAtomicAdd(Out + (size_t)cur * NC + gc1 + j, sB[j]);
                    }
                }
                cur = b;
#pragma unroll
                for (int j = 0; j < 4; ++j) { sA[j] = 0.f; sB[j] = 0.f; }
            }
            if (b >= 0) {
#pragma unroll
                for (int j = 0; j < 4; ++j) {
                    sA[j] += ssp(acc[i][j]);
                    sB[j] += ssp(acc[i][4 + j]);
                }
            }
        }
        if (cur >= 0) {
#pragma unroll
            for (int j = 0; j < 4; ++j) {
                unsafeAtomicAdd(Out + (size_t)cur * NC + gc0 + j, sA[j]);
                unsafeAtomicAdd(Out + (size_t)cur * NC + gc1 + j, sB[j]);
            }
        }
    } else {
#pragma unroll
        for (int i = 0; i < 4; ++i) {
            int r = r0 + i;
            if (r >= rlim) break;
            float* orow = Out + (size_t)(rowBase + r) * NC;
            float4 vA = make_float4(acc[i][0], acc[i][1], acc[i][2], acc[i][3]);
            float4 vB = make_float4(acc[i][4], acc[i][5], acc[i][6], acc[i][7]);
            if (FLAGS & F_ACCUM) {
                float4 oA = *(float4*)(orow + gc0);
                float4 oB = *(float4*)(orow + gc1);
                vA.x += oA.x; vA.y += oA.y; vA.z += oA.z; vA.w += oA.w;
                vB.x += oB.x; vB.y += oB.y; vB.z += oB.z; vB.w += oB.w;
            }
            *(float4*)(orow + gc0) = vA;
            *(float4*)(orow + gc1) = vB;
        }
    }
}

// -------------------- fused edge kernel v3 --------------------
// 64 edges / 128 threads (2 waves = col halves). Full-Tt publish kills the
// acc/acc2 register overlap (no AGPR spill). Full-Wfs publish kills acc2
// before the scatter. x-gather prefetched 32-deep. PRESORTED variant streams
// pre-permuted attrs (coalesced) instead of gathering.
template <bool PRESORTED>
__global__ __launch_bounds__(128, 2) void edge_kernel(const float* __restrict__ attrp,
                                                      const int* __restrict__ perm,
                                                      const int* __restrict__ srcp,
                                                      const int* __restrict__ dstp,
                                                      const float* __restrict__ cwp,
                                                      const float* __restrict__ W1,
                                                      const float* __restrict__ b1,
                                                      const float* __restrict__ W2,
                                                      const float* __restrict__ b2,
                                                      const float* __restrict__ x,
                                                      float* __restrict__ agg) {
    __shared__ float buf[8512];        // attrT[50][68] -> Tt[128][66] -> Wfs[64][133]
    __shared__ int Se[64], De[64], Ge[64];
    __shared__ float Cs[64];
    __shared__ int bnd[2];

    int tid = threadIdx.x;
    int e0 = blockIdx.x * 64;
    int lane = tid & 63;
    int cbase = __builtin_amdgcn_readfirstlane((tid >> 6) * 64);   // 0 or 64, SGPR

    if (PRESORTED) {
        if (tid < 64) {
            Se[tid] = srcp[e0 + tid];
            De[tid] = dstp[e0 + tid];
            Cs[tid] = cwp[e0 + tid];
        }
        if (tid == 64) bnd[0] = (e0 > 0) ? dstp[e0 - 1] : -1;
        if (tid == 65) bnd[1] = (e0 + 64 < N_EDGES) ? dstp[e0 + 64] : -1;
    } else {
        if (tid < 64) {
            int ge = perm[e0 + tid];
            Ge[tid] = ge;
            Se[tid] = srcp[ge];
            De[tid] = dstp[ge];
            Cs[tid] = 0.5f * (cosf(cwp[ge] * (PI_F / 10.0f)) + 1.0f);
        }
        if (tid == 64) bnd[0] = (e0 > 0) ? dstp[perm[e0 - 1]] : -1;
        if (tid == 65) bnd[1] = (e0 + 64 < N_EDGES) ? dstp[perm[e0 + 64]] : -1;
    }
    __syncthreads();

    // ---- stage attr transposed [k][e], ld 68 ----
    float* attrT = buf;
    if (PRESORTED) {
        const float* src = attrp + (size_t)e0 * NG;    // contiguous 12.8 KB
        for (int idx4 = tid; idx4 < 800; idx4 += 128) {
            float4 v = *(const float4*)(src + idx4 * 4);
            int f = idx4 * 4;
#pragma unroll
            for (int j = 0; j < 4; ++j) {
                int e = (f + j) / NG, k = (f + j) - e * NG;
                attrT[k * 68 + e] = (&v.x)[j];
            }
        }
    } else {
        for (int idx = tid; idx < 64 * NG; idx += 128) {
            int e = idx / NG, k = idx - e * NG;
            attrT[k * 68 + e] = attrp[(size_t)Ge[e] * NG + k];
        }
    }
    __syncthreads();

    // ---- GEMM1: acc[c] = b1 + attr @ W1 (W rows wave-uniform -> s_load) ----
    float acc[64];
#pragma unroll
    for (int c4 = 0; c4 < 16; ++c4) {
        float4 b = *(const float4*)(b1 + cbase + c4 * 4);
        acc[c4 * 4 + 0] = b.x; acc[c4 * 4 + 1] = b.y;
        acc[c4 * 4 + 2] = b.z; acc[c4 * 4 + 3] = b.w;
    }
#pragma unroll 2
    for (int k = 0; k < NG; ++k) {
        float tk = attrT[k * 68 + lane];
        const float* wr = W1 + (size_t)k * H + cbase;
#pragma unroll
        for (int c4 = 0; c4 < 16; ++c4) {
            float4 w = *(const float4*)(wr + c4 * 4);
            acc[c4 * 4 + 0] = fmaf(tk, w.x, acc[c4 * 4 + 0]);
            acc[c4 * 4 + 1] = fmaf(tk, w.y, acc[c4 * 4 + 1]);
            acc[c4 * 4 + 2] = fmaf(tk, w.z, acc[c4 * 4 + 2]);
            acc[c4 * 4 + 3] = fmaf(tk, w.w, acc[c4 * 4 + 3]);
        }
    }
    __syncthreads();   // attrT dead

    // ---- publish FULL Tt[128][66] (both waves) -> acc dies here ----
    float* Tt = buf;
#pragma unroll
    for (int c = 0; c < 64; ++c)
        Tt[(cbase + c) * 66 + lane] = ssp(acc[c]);
    __syncthreads();

    // ---- GEMM2: acc2 = b2 + T @ W2 ----
    float acc2[64];
#pragma unroll
    for (int c4 = 0; c4 < 16; ++c4) {
        float4 b = *(const float4*)(b2 + cbase + c4 * 4);
        acc2[c4 * 4 + 0] = b.x; acc2[c4 * 4 + 1] = b.y;
        acc2[c4 * 4 + 2] = b.z; acc2[c4 * 4 + 3] = b.w;
    }
#pragma unroll 2
    for (int k = 0; k < H; ++k) {
        float tk = Tt[k * 66 + lane];
        const float* wr = W2 + (size_t)k * H + cbase;
#pragma unroll
        for (int c4 = 0; c4 < 16; ++c4) {
            float4 w = *(const float4*)(wr + c4 * 4);
            acc2[c4 * 4 + 0] = fmaf(tk, w.x, acc2[c4 * 4 + 0]);
            acc2[c4 * 4 + 1] = fmaf(tk, w.y, acc2[c4 * 4 + 1]);
            acc2[c4 * 4 + 2] = fmaf(tk, w.z, acc2[c4 * 4 + 2]);
            acc2[c4 * 4 + 3] = fmaf(tk, w.w, acc2[c4 * 4 + 3]);
        }
    }
    __syncthreads();   // Tt dead

    // ---- publish FULL Wfs[64][133] = acc2 * C -> acc2 dies here ----
    float cf = Cs[lane];
    float* Wfs = buf;
#pragma unroll
    for (int c4 = 0; c4 < 16; ++c4)
        *(float4*)(Wfs + lane * 133 + cbase + c4 * 4) =
            make_float4(acc2[c4 * 4 + 0] * cf, acc2[c4 * 4 + 1] * cf,
                        acc2[c4 * 4 + 2] * cf, acc2[c4 * 4 + 3] * cf);
    __syncthreads();

    // ---- scatter: lane = column (128 cols), run-compacted over 64 sorted edges,
    //      x-gather prefetched in 2 windows of 32 ----
    int c = tid;
    int prevd = bnd[0], nextd = bnd[1];
    float rsum = 0.f;
    bool first = true;
    for (int w = 0; w < 2; ++w) {
        int ebase = w * 32;
        float xv[32];
#pragma unroll
        for (int e = 0; e < 32; ++e)
            xv[e] = x[(size_t)Se[ebase + e] * H + c];
#pragma unroll 4
        for (int e = 0; e < 32; ++e) {
            int ge = ebase + e;
            rsum = fmaf(Wfs[ge * 133 + c], xv[e], rsum);
            int d = De[ge];
            int nd = (ge < 63) ? De[ge + 1] : nextd;
            if (d != nd) {             // end of run (wave-uniform branch)
                float* p = agg + (size_t)d * H + c;
                if (first && d == prevd) unsafeAtomicAdd(p, rsum);
                else *p = rsum;
                rsum = 0.f;
                first = false;
            }
        }
    }
    if (De[63] == nextd)               // pending run crosses into next block
        unsafeAtomicAdd(agg + (size_t)De[63] * H + c, rsum);
}

// -------------------- out = ssp(pooled@ro_w2 + b2) @ ro_w3 + b3 --------------------
__global__ __launch_bounds__(128) void final_out(const float* __restrict__ pooled,
                                                 const float* __restrict__ ro_w2,
                                                 const float* __restrict__ ro_b2,
                                                 const float* __restrict__ ro_w3,
                                                 const float* __restrict__ ro_b3,
                                                 float* __restrict__ out) {
    int g = blockIdx.x;
    int c = threadIdx.x;
    float acc = ro_b2[c];
    const float* pr = pooled + (size_t)g * (5 * H);
    for (int k = 0; k < 5 * H; ++k) acc = fmaf(pr[k], ro_w2[(size_t)k * H + c], acc);
    float v = ssp(acc) * ro_w3[c];
    __shared__ float red[128];
    red[c] = v;
    __syncthreads();
    for (int s = 64; s > 0; s >>= 1) {
        if (c < s) red[c] += red[c + s];
        __syncthreads();
    }
    if (c == 0) out[g] = red[0] + ro_b3[0];
}

extern "C" void kernel_launch(void* const* d_in, const int* in_sizes, int n_in,
                              void* d_out, int out_size, void* d_ws, size_t ws_size,
                              hipStream_t stream) {
    const int* z     = (const int*)d_in[0];
    const int* esrc  = (const int*)d_in[1];
    const int* edst  = (const int*)d_in[2];
    const int* batch = (const int*)d_in[3];
    const float* ew    = (const float*)d_in[5];
    const float* eattr = (const float*)d_in[6];
    const float* emb   = (const float*)d_in[7];
    const float* mlp_w1 = (const float*)d_in[8];
    const float* mlp_b1 = (const float*)d_in[9];
    const float* mlp_w2 = (const float*)d_in[10];
    const float* mlp_b2 = (const float*)d_in[11];
    const float* cf_w1  = (const float*)d_in[12];
    const float* cf_w2  = (const float*)d_in[13];
    const float* cf_b2  = (const float*)d_in[14];
    const float* lin_w  = (const float*)d_in[15];
    const float* lin_b  = (const float*)d_in[16];
    const float* ro_w1  = (const float*)d_in[17];
    const float* ro_b1  = (const float*)d_in[18];
    const float* ro_w2  = (const float*)d_in[19];
    const float* ro_b2  = (const float*)d_in[20];
    const float* ro_w3  = (const float*)d_in[21];
    const float* ro_b3  = (const float*)d_in[22];
    float* out = (float*)d_out;

    float* h      = (float*)d_ws;
    float* x      = h + (size_t)N_NODES * H;
    float* agg    = x + (size_t)N_NODES * H;
    float* pooled = agg + (size_t)N_NODES * H;
    int*   cnt    = (int*)(pooled + (size_t)G_GRAPHS * 5 * H);
    int*   cur    = cnt + N_NODES;
    int*   perm   = cur + N_NODES;
    int*   esrc_s = perm + N_EDGES;
    int*   edst_s = esrc_s + N_EDGES;
    float* cw_s   = (float*)(edst_s + N_EDGES);
    float* eattr_s = cw_s + N_EDGES;
    size_t need = ((size_t)(eattr_s - (float*)d_ws) + (size_t)N_EDGES * NG) * sizeof(float);
    bool presorted = (ws_size >= need);   // ws_size constant per session -> same work every call

    init_h<<<(N_NODES * (H / 4) + 255) / 256, 256, 0, stream>>>(z, emb, h);

    // CSR build (once; reused by all 3 layers)
    hipMemsetAsync(cnt, 0, N_NODES * sizeof(int), stream);
    hist_kernel<<<(N_EDGES + 255) / 256, 256, 0, stream>>>(edst, cnt);
    scan_kernel<<<1, 1024, 0, stream>>>(cnt, cur);
    scatter_kernel<<<(N_EDGES + 255) / 256, 256, 0, stream>>>(edst, cur, perm);
    if (presorted) {
        presort_meta<<<(N_EDGES + 255) / 256, 256, 0, stream>>>(
            ew, esrc, edst, perm, esrc_s, edst_s, cw_s);
        presort_attr<<<(int)(((long long)N_EDGES * 64) / 256), 256, 0, stream>>>(
            eattr, perm, eattr_s);
    }

    int rowTiles = (N_NODES + 63) / 64;  // 782
    for (int l = 0; l < LAYERS; ++l) {
        node_gemm<0><<<dim3(rowTiles, 1), 256, 0, stream>>>(
            h, cf_w1 + (size_t)l * H * H, nullptr, x, nullptr, N_NODES, H);
        hipMemsetAsync(agg, 0, (size_t)N_NODES * H * sizeof(float), stream);
        if (presorted)
            edge_kernel<true><<<N_EDGES / 64, 128, 0, stream>>>(
                eattr_s, perm, esrc_s, edst_s, cw_s,
                mlp_w1 + (size_t)l * NG * H, mlp_b1 + (size_t)l * H,
                mlp_w2 + (size_t)l * H * H, mlp_b2 + (size_t)l * H, x, agg);
        else
            edge_kernel<false><<<N_EDGES / 64, 128, 0, stream>>>(
                eattr, perm, esrc, edst, ew,
                mlp_w1 + (size_t)l * NG * H, mlp_b1 + (size_t)l * H,
                mlp_w2 + (size_t)l * H * H, mlp_b2 + (size_t)l * H, x, agg);
        node_gemm<F_BIAS><<<dim3(rowTiles, 1), 256, 0, stream>>>(
            agg, cf_w2 + (size_t)l * H * H, cf_b2 + (size_t)l * H, x, nullptr, N_NODES, H);
        node_gemm<F_BIAS | F_SSPA | F_ACCUM><<<dim3(rowTiles, 1), 256, 0, stream>>>(
            x, lin_w + (size_t)l * H * H, lin_b + (size_t)l * H, h, nullptr, N_NODES, H);
    }

    hipMemsetAsync(pooled, 0, (size_t)G_GRAPHS * 5 * H * sizeof(float), stream);
    node_gemm<F_BIAS | F_POOL><<<dim3(rowTiles, 5), 256, 0, stream>>>(
        h, ro_w1, ro_b1, pooled, batch, N_NODES, 5 * H);
    final_out<<<G_GRAPHS, 128, 0, stream>>>(pooled, ro_w2, ro_b2, ro_w3, ro_b3, out);
}